// Round 1
// baseline (488.356 us; speedup 1.0000x reference)
//
#include <hip/hip_runtime.h>
#include <math.h>

// Problem constants: B=1, H=32, S=2048, D=128, N_OUT=16, QMAX=7, EPS=1e-6
// Key insight: top-k indices are never needed. Per slice we need only the
// 16th largest |x| (outlier membership threshold) and 17th largest (scale).

typedef __bf16 bf16x8 __attribute__((ext_vector_type(8)));
typedef __bf16 bf16x4 __attribute__((ext_vector_type(4)));
typedef float f32x4 __attribute__((ext_vector_type(4)));

#define H 32
#define S 2048
#define D 128

// ---------------------------------------------------------------------------
// Kernel A: K reconstruction. One wave per (h,d) slice (outliers along tokens).
// Writes bf16 k_rec[h][s][d].
// ---------------------------------------------------------------------------
__global__ __launch_bounds__(256) void krecon_kernel(const float* __restrict__ K,
                                                     __bf16* __restrict__ k_rec) {
    const int h = blockIdx.y;
    const int wv = threadIdx.x >> 6;
    const int lane = threadIdx.x & 63;
    const int d = blockIdx.x * 4 + wv;

    const float* base = K + (size_t)h * S * D + d;
    float v[32], av[32];
#pragma unroll
    for (int i = 0; i < 32; ++i) {
        v[i] = base[(size_t)(i * 64 + lane) * D];
        av[i] = fabsf(v[i]);
    }
    // 17 rounds of select-max-and-remove -> exact 16th/17th order statistics
    float thr16 = 0.f, thr17 = 0.f;
    for (int t = 0; t < 17; ++t) {
        float lm = -1.f; int li = 0;
#pragma unroll
        for (int i = 0; i < 32; ++i) { if (av[i] > lm) { lm = av[i]; li = i; } }
        float gm = lm;
#pragma unroll
        for (int off = 1; off < 64; off <<= 1) gm = fmaxf(gm, __shfl_xor(gm, off));
        unsigned long long ball = __ballot(lm == gm);
        int owner = __ffsll(ball) - 1;          // remove exactly one instance
        if (lane == owner) av[li] = -1.f;
        if (t == 15) thr16 = gm;
        else if (t == 16) thr17 = gm;
    }
    const float scale = fmaxf(thr17, 1e-6f) / 7.0f;   // match ref: max(.,EPS)/QMAX
    __bf16* ob = k_rec + (size_t)h * S * D + d;
#pragma unroll
    for (int i = 0; i < 32; ++i) {
        float x = v[i];
        float o;
        if (fabsf(x) >= thr16) {
            o = x;                               // outlier kept exact
        } else {
            float q = rintf(x / scale);          // RNE, matches jnp.round
            q = fminf(fmaxf(q, -7.f), 7.f);
            o = q * scale;
        }
        ob[(size_t)(i * 64 + lane) * D] = (__bf16)o;
    }
}

// ---------------------------------------------------------------------------
// Kernel B: V reconstruction. One wave per (h,s) row (outliers along channels).
// Writes TRANSPOSED bf16 vT[h][d][s] (coalesced via LDS tile) so attention's
// MFMA B-fragments read 8 contiguous bf16 per lane.
// ---------------------------------------------------------------------------
__global__ __launch_bounds__(256) void vrecon_kernel(const float* __restrict__ V,
                                                     __bf16* __restrict__ vT) {
    __shared__ __bf16 tile[128][72];   // [d][s_rel], stride 72 -> 144B rows (16B aligned)
    const int h = blockIdx.y;
    const int s0 = blockIdx.x * 64;
    const int wv = threadIdx.x >> 6;
    const int lane = threadIdx.x & 63;

    for (int it = 0; it < 16; ++it) {
        const int s = s0 + wv * 16 + it;
        const float* row = V + ((size_t)h * S + s) * D;
        const float a = row[lane], b = row[lane + 64];
        float r0 = fabsf(a), r1 = fabsf(b);
        const float aa = r0, ab = r1;
        float thr16 = 0.f, thr17 = 0.f;
        for (int t = 0; t < 17; ++t) {
            float lm = fmaxf(r0, r1);
            float gm = lm;
#pragma unroll
            for (int off = 1; off < 64; off <<= 1) gm = fmaxf(gm, __shfl_xor(gm, off));
            unsigned long long ball = __ballot(lm == gm);
            int owner = __ffsll(ball) - 1;
            if (lane == owner) { if (r0 == gm) r0 = -1.f; else r1 = -1.f; }
            if (t == 15) thr16 = gm;
            else if (t == 16) thr17 = gm;
        }
        const float scale = fmaxf(thr17, 1e-6f) / 7.0f;
        float o0, o1;
        if (aa >= thr16) o0 = a;
        else { float q = rintf(a / scale); q = fminf(fmaxf(q, -7.f), 7.f); o0 = q * scale; }
        if (ab >= thr16) o1 = b;
        else { float q = rintf(b / scale); q = fminf(fmaxf(q, -7.f), 7.f); o1 = q * scale; }
        const int srel = wv * 16 + it;
        tile[lane][srel] = (__bf16)o0;
        tile[lane + 64][srel] = (__bf16)o1;
    }
    __syncthreads();
    // coalesced transposed write-out: vT[h][d][s0..s0+63]
    const int dRow = threadIdx.x >> 3;   // 0..31
    const int c3 = threadIdx.x & 7;      // 16B chunk
#pragma unroll
    for (int i = 0; i < 4; ++i) {
        const int d = dRow + 32 * i;
        bf16x8 val = *(const bf16x8*)&tile[d][c3 * 8];
        *(bf16x8*)&vT[((size_t)h * D + d) * S + s0 + c3 * 8] = val;
    }
}

// ---------------------------------------------------------------------------
// Kernel C: Q -> bf16 cast (elementwise).
// ---------------------------------------------------------------------------
__global__ __launch_bounds__(256) void qcast_kernel(const float* __restrict__ Q,
                                                    __bf16* __restrict__ qb) {
    const size_t idx = ((size_t)blockIdx.x * 256 + threadIdx.x) * 4;
    const float4 v = *(const float4*)(Q + idx);
    bf16x4 o = { (__bf16)v.x, (__bf16)v.y, (__bf16)v.z, (__bf16)v.w };
    *(bf16x4*)(qb + idx) = o;
}

// ---------------------------------------------------------------------------
// Kernel D: causal flash attention, bf16 MFMA 16x16x32.
// Block = 4 waves = 64 query rows; key tiles of 64; online softmax.
// A-layout: A[m=lane&15][k=quad*8+j]; C/D: col=lane&15, row=quad*4+reg.
// P goes C-layout -> LDS -> A-layout (verified m120 recipe).
// ---------------------------------------------------------------------------
__global__ __launch_bounds__(256) void attn_kernel(const __bf16* __restrict__ qb,
                                                   const __bf16* __restrict__ k_rec,
                                                   const __bf16* __restrict__ vT,
                                                   float* __restrict__ out) {
    __shared__ __bf16 Kl[64][136];      // [key][ch], stride 136 -> 272B rows, 2-way banks
    __shared__ __bf16 Vt[128][72];      // [ch][key], stride 72  -> 144B rows, 2-way banks
    __shared__ __bf16 Pl[4][16][72];    // per-wave P [q][key]

    const int qblk = blockIdx.x;        // 0..31
    const int h = blockIdx.y;
    const int tid = threadIdx.x;
    const int wv = tid >> 6;
    const int lane = tid & 63;
    const int quad = lane >> 4;
    const int col = lane & 15;
    const int q0 = qblk * 64;
    const int qr0 = q0 + wv * 16;

    // Q fragments for this wave's 16 rows (K-dim = 128 -> 4 frags of K=32)
    bf16x8 qf[4];
    {
        const __bf16* qbase = qb + ((size_t)h * S + qr0 + col) * D + quad * 8;
#pragma unroll
        for (int kk = 0; kk < 4; ++kk) qf[kk] = *(const bf16x8*)(qbase + kk * 32);
    }

    f32x4 oacc[8];
#pragma unroll
    for (int dt = 0; dt < 8; ++dt) oacc[dt] = (f32x4){0.f, 0.f, 0.f, 0.f};
    float mrun[4] = {-INFINITY, -INFINITY, -INFINITY, -INFINITY};
    float lrun[4] = {0.f, 0.f, 0.f, 0.f};
    const float inv_sqrt_d = 0.08838834764831845f;

    const int rowq16 = tid >> 4, chunk = tid & 15;   // K staging
    const int dRow = tid >> 3, c3 = tid & 7;         // V staging

    for (int kt = 0; kt <= qblk; ++kt) {
        __syncthreads();   // protect prior iteration's LDS reads
        // stage K tile [64 x 128] and V tile (transposed) [128 x 64]
#pragma unroll
        for (int i = 0; i < 4; ++i) {
            const int key = rowq16 + 16 * i;
            *(bf16x8*)&Kl[key][chunk * 8] =
                *(const bf16x8*)&k_rec[((size_t)h * S + kt * 64 + key) * D + chunk * 8];
        }
#pragma unroll
        for (int i = 0; i < 4; ++i) {
            const int d = dRow + 32 * i;
            *(bf16x8*)&Vt[d][c3 * 8] =
                *(const bf16x8*)&vT[((size_t)h * D + d) * S + kt * 64 + c3 * 8];
        }
        __syncthreads();

        // S = Q(16x128) @ K_tile^T(128x64): 4 col-tiles x 4 K-steps
        f32x4 sacc[4];
#pragma unroll
        for (int c = 0; c < 4; ++c) sacc[c] = (f32x4){0.f, 0.f, 0.f, 0.f};
#pragma unroll
        for (int kk = 0; kk < 4; ++kk) {
#pragma unroll
            for (int c = 0; c < 4; ++c) {
                bf16x8 bfrag = *(const bf16x8*)&Kl[c * 16 + col][kk * 32 + quad * 8];
                sacc[c] = __builtin_amdgcn_mfma_f32_16x16x32_bf16(qf[kk], bfrag, sacc[c], 0, 0, 0);
            }
        }

        // scale + causal mask (only the diagonal tile needs masking)
        float sv[4][4];
        const bool diag = (kt == qblk);
#pragma unroll
        for (int c = 0; c < 4; ++c) {
#pragma unroll
            for (int r = 0; r < 4; ++r) {
                float val = sacc[c][r] * inv_sqrt_d;
                if (diag) {
                    const int key = c * 16 + col;
                    const int qrow = wv * 16 + quad * 4 + r;
                    if (key > qrow) val = -INFINITY;
                }
                sv[c][r] = val;
            }
        }

        // online softmax: row stats live on the 16 lanes of each quad group
        float ps[4][4];
#pragma unroll
        for (int r = 0; r < 4; ++r) {
            float mt = fmaxf(fmaxf(sv[0][r], sv[1][r]), fmaxf(sv[2][r], sv[3][r]));
#pragma unroll
            for (int off = 1; off < 16; off <<= 1) mt = fmaxf(mt, __shfl_xor(mt, off));
            const float mnew = fmaxf(mrun[r], mt);
            const float alpha = __expf(mrun[r] - mnew);   // exp(-inf)=0 on first tile
            mrun[r] = mnew;
            float lad = 0.f;
#pragma unroll
            for (int c = 0; c < 4; ++c) {
                const float p = __expf(sv[c][r] - mnew);
                ps[c][r] = p;
                lad += p;
            }
#pragma unroll
            for (int off = 1; off < 16; off <<= 1) lad += __shfl_xor(lad, off);
            lrun[r] = lrun[r] * alpha + lad;
#pragma unroll
            for (int dt = 0; dt < 8; ++dt) oacc[dt][r] *= alpha;
        }

        // P: C-layout regs -> LDS [q][key] for A-layout reads
#pragma unroll
        for (int c = 0; c < 4; ++c)
#pragma unroll
            for (int r = 0; r < 4; ++r)
                Pl[wv][quad * 4 + r][c * 16 + col] = (__bf16)ps[c][r];
        __syncthreads();

        // O += P(16x64) @ V(64x128): 2 K-steps x 8 d-tiles
#pragma unroll
        for (int ks = 0; ks < 2; ++ks) {
            bf16x8 af = *(const bf16x8*)&Pl[wv][col][ks * 32 + quad * 8];
#pragma unroll
            for (int dt = 0; dt < 8; ++dt) {
                bf16x8 bfrag = *(const bf16x8*)&Vt[dt * 16 + col][ks * 32 + quad * 8];
                oacc[dt] = __builtin_amdgcn_mfma_f32_16x16x32_bf16(af, bfrag, oacc[dt], 0, 0, 0);
            }
        }
    }

    // epilogue: normalize and store fp32
#pragma unroll
    for (int r = 0; r < 4; ++r) {
        const float inv_l = 1.0f / lrun[r];
        const int qrow = q0 + wv * 16 + quad * 4 + r;
        float* ob = out + ((size_t)h * S + qrow) * D;
#pragma unroll
        for (int dt = 0; dt < 8; ++dt)
            ob[dt * 16 + col] = oacc[dt][r] * inv_l;
    }
}

// ---------------------------------------------------------------------------
extern "C" void kernel_launch(void* const* d_in, const int* in_sizes, int n_in,
                              void* d_out, int out_size, void* d_ws, size_t ws_size,
                              hipStream_t stream) {
    const float* Q = (const float*)d_in[0];
    const float* K = (const float*)d_in[1];
    const float* V = (const float*)d_in[2];
    float* out = (float*)d_out;

    char* ws = (char*)d_ws;
    const size_t nElem = (size_t)H * S * D;          // 8,388,608
    __bf16* k_rec = (__bf16*)ws;                     // 16.78 MB
    __bf16* vT    = (__bf16*)(ws + nElem * 2);       // 16.78 MB (transposed [h][d][s])
    __bf16* q_bf  = (__bf16*)(ws + nElem * 4);       // 16.78 MB

    krecon_kernel<<<dim3(32, H), 256, 0, stream>>>(K, k_rec);
    vrecon_kernel<<<dim3(S / 64, H), 256, 0, stream>>>(V, vT);
    qcast_kernel<<<dim3(nElem / 1024), 256, 0, stream>>>(Q, q_bf);
    attn_kernel<<<dim3(S / 64, H), 256, 0, stream>>>(q_bf, k_rec, vT, out);
}

// Round 2
// 377.068 us; speedup vs baseline: 1.2951x; 1.2951x over previous
//
#include <hip/hip_runtime.h>
#include <math.h>

// B=1, H=32, S=2048, D=128, N_OUT=16, QMAX=7, EPS=1e-6
// Top-k indices never needed: only 16th (outlier threshold, kept exact) and
// 17th (scale) order statistics of |x| per slice.

typedef __bf16 bf16x8 __attribute__((ext_vector_type(8)));
typedef __bf16 bf16x4 __attribute__((ext_vector_type(4)));
typedef float f32x4 __attribute__((ext_vector_type(4)));

#define H 32
#define S 2048
#define D 128

// ---------------------------------------------------------------------------
// K path, phase 1: per-(h,ch) partial top-17 over token chunks, coalesced.
// Branch-free sorted-insert: t'[j] = med3(x, t[j-1], t[j]) (desc order).
// Grid (8, 32): 8 token-chunks of 256, 256 threads (128 ch x 2 token slots).
// ---------------------------------------------------------------------------
__global__ __launch_bounds__(256) void kstats_kernel(const float* __restrict__ K,
                                                     float* __restrict__ cand) {
    const int h = blockIdx.y, tq = blockIdx.x;
    const int ch = threadIdx.x & 127, ts = threadIdx.x >> 7;
    const float* p = K + ((size_t)h * S + tq * 256 + ts) * D + ch;
    float t[17];
#pragma unroll
    for (int j = 0; j < 17; ++j) t[j] = -1.f;
#pragma unroll 4
    for (int i = 0; i < 128; ++i) {
        const float x = fabsf(p[(size_t)i * 256]);   // tokens ts, ts+2, ...
#pragma unroll
        for (int j = 16; j >= 1; --j) t[j] = __builtin_amdgcn_fmed3f(x, t[j - 1], t[j]);
        t[0] = fmaxf(t[0], x);
    }
    float* o = cand + ((size_t)(h * 128 + ch) * 16 + tq * 2 + ts) * 17;
#pragma unroll
    for (int j = 0; j < 17; ++j) o[j] = t[j];
}

// ---------------------------------------------------------------------------
// K path, phase 2: merge 16 partial lists per (h,ch) -> thr16 + scale table.
// 4096 threads, 272 contiguous floats each through the same med3 chain.
// ---------------------------------------------------------------------------
__global__ __launch_bounds__(256) void kmerge_kernel(const float* __restrict__ cand,
                                                     float2* __restrict__ ktab) {
    const int g = blockIdx.x * 256 + threadIdx.x;    // (h*128+ch)
    const float* p = cand + (size_t)g * 272;
    float t[17];
#pragma unroll
    for (int j = 0; j < 17; ++j) t[j] = -1.f;
#pragma unroll 4
    for (int i = 0; i < 272; ++i) {
        const float x = p[i];
#pragma unroll
        for (int j = 16; j >= 1; --j) t[j] = __builtin_amdgcn_fmed3f(x, t[j - 1], t[j]);
        t[0] = fmaxf(t[0], x);
    }
    ktab[g] = make_float2(t[15], fmaxf(t[16], 1e-6f) / 7.0f);   // thr16, scale
}

// ---------------------------------------------------------------------------
// K path, phase 3: elementwise fake-quant apply, fully coalesced.
// ---------------------------------------------------------------------------
__global__ __launch_bounds__(256) void kapply_kernel(const float* __restrict__ K,
                                                     const float2* __restrict__ ktab,
                                                     __bf16* __restrict__ k_rec) {
    const size_t base = ((size_t)blockIdx.x * 256 + threadIdx.x) * 4;
    const int h = (int)(base >> 18);            // S*D = 2^18
    const int d0 = (int)(base & (D - 1));
    const float4 x = *(const float4*)(K + base);
    const float2* tp = ktab + h * D + d0;
    float xs[4] = {x.x, x.y, x.z, x.w};
    bf16x4 o;
#pragma unroll
    for (int c = 0; c < 4; ++c) {
        const float2 tc = tp[c];
        float v;
        if (fabsf(xs[c]) >= tc.x) v = xs[c];
        else {
            float q = rintf(xs[c] / tc.y);
            q = fminf(fmaxf(q, -7.f), 7.f);
            v = q * tc.y;
        }
        o[c] = (__bf16)v;
    }
    *(bf16x4*)(k_rec + base) = o;
}

// ---------------------------------------------------------------------------
// V reconstruction: one wave per (h,s) row, outliers along channels.
// Writes transposed bf16 vT[h][d][s]; LDS writes buffered to ds_write_b128.
// ---------------------------------------------------------------------------
__global__ __launch_bounds__(256) void vrecon_kernel(const float* __restrict__ V,
                                                     __bf16* __restrict__ vT) {
    __shared__ __bf16 tile[128][72];
    const int h = blockIdx.y;
    const int s0 = blockIdx.x * 64;
    const int wv = threadIdx.x >> 6;
    const int lane = threadIdx.x & 63;

#pragma unroll
    for (int g = 0; g < 2; ++g) {
        bf16x8 b0, b1;
#pragma unroll
        for (int it = 0; it < 8; ++it) {
            const int s = s0 + wv * 16 + g * 8 + it;
            const float* row = V + ((size_t)h * S + s) * D;
            const float a = row[lane], b = row[lane + 64];
            float r0 = fabsf(a), r1 = fabsf(b);
            const float aa = r0, ab = r1;
            float thr16 = 0.f, thr17 = 0.f;
            for (int t = 0; t < 17; ++t) {
                float lm = fmaxf(r0, r1);
                float gm = lm;
#pragma unroll
                for (int off = 1; off < 64; off <<= 1) gm = fmaxf(gm, __shfl_xor(gm, off));
                unsigned long long ball = __ballot(lm == gm);
                int owner = __ffsll(ball) - 1;
                if (lane == owner) { if (r0 == gm) r0 = -1.f; else r1 = -1.f; }
                if (t == 15) thr16 = gm;
                else if (t == 16) thr17 = gm;
            }
            const float scale = fmaxf(thr17, 1e-6f) / 7.0f;
            float o0, o1;
            if (aa >= thr16) o0 = a;
            else { float q = rintf(a / scale); q = fminf(fmaxf(q, -7.f), 7.f); o0 = q * scale; }
            if (ab >= thr16) o1 = b;
            else { float q = rintf(b / scale); q = fminf(fmaxf(q, -7.f), 7.f); o1 = q * scale; }
            b0[it] = (__bf16)o0;
            b1[it] = (__bf16)o1;
        }
        *(bf16x8*)&tile[lane][wv * 16 + g * 8] = b0;
        *(bf16x8*)&tile[lane + 64][wv * 16 + g * 8] = b1;
    }
    __syncthreads();
    const int dRow = threadIdx.x >> 3;
    const int c3 = threadIdx.x & 7;
#pragma unroll
    for (int i = 0; i < 4; ++i) {
        const int d = dRow + 32 * i;
        bf16x8 val = *(const bf16x8*)&tile[d][c3 * 8];
        *(bf16x8*)&vT[((size_t)h * D + d) * S + s0 + c3 * 8] = val;
    }
}

// ---------------------------------------------------------------------------
// Causal flash attention, bf16 MFMA 16x16x32.
// Block = 4 waves = 64 q-rows; paired q-blocks (i, 31-i) -> uniform 33 tiles.
// Register-prefetch of next K/V tile across the barrier; per-wave P buffer
// (no barrier after P write); deferred l-reduce; exp2-domain softmax.
// ---------------------------------------------------------------------------
__global__ __launch_bounds__(256, 3) void attn_kernel(const float* __restrict__ Q,
                                                      const __bf16* __restrict__ k_rec,
                                                      const __bf16* __restrict__ vT,
                                                      float* __restrict__ out) {
    __shared__ __bf16 Kl[64][136];
    __shared__ __bf16 Vt[128][72];
    __shared__ __bf16 Pl[4][16][72];

    const int h = blockIdx.y;
    const int tid = threadIdx.x;
    const int wv = tid >> 6;
    const int lane = tid & 63;
    const int quad = lane >> 4;
    const int col = lane & 15;
    const int rowq16 = tid >> 4, chunk = tid & 15;   // K staging
    const int dRow = tid >> 3, c3 = tid & 7;         // V staging
    const __bf16* kb = k_rec + (size_t)h * S * D;
    const __bf16* vb = vT + (size_t)h * D * S;
    const float kscale = 0.08838834764831845f * 1.4426950408889634f;  // 1/sqrt(D)*log2(e)

#pragma unroll 1
    for (int phase = 0; phase < 2; ++phase) {
        const int qblk = (phase == 0) ? blockIdx.x : 31 - blockIdx.x;
        const int q0 = qblk * 64;
        const int qr0 = q0 + wv * 16;

        // Q fragments, fp32 -> bf16 in-kernel (once per q-block)
        bf16x8 qf[4];
        {
            const float* qbase = Q + ((size_t)h * S + qr0 + col) * D + quad * 8;
#pragma unroll
            for (int kk = 0; kk < 4; ++kk) {
                const float4 a = *(const float4*)(qbase + kk * 32);
                const float4 b = *(const float4*)(qbase + kk * 32 + 4);
                qf[kk] = (bf16x8){(__bf16)a.x, (__bf16)a.y, (__bf16)a.z, (__bf16)a.w,
                                  (__bf16)b.x, (__bf16)b.y, (__bf16)b.z, (__bf16)b.w};
            }
        }

        f32x4 oacc[8];
#pragma unroll
        for (int dt = 0; dt < 8; ++dt) oacc[dt] = (f32x4){0.f, 0.f, 0.f, 0.f};
        float mrun[4] = {-INFINITY, -INFINITY, -INFINITY, -INFINITY};
        float lrun[4] = {0.f, 0.f, 0.f, 0.f};   // per-lane partial sums

        // prefetch tile 0 into registers
        bf16x8 kreg[4], vreg[4];
#pragma unroll
        for (int i = 0; i < 4; ++i) {
            kreg[i] = *(const bf16x8*)&kb[(size_t)(rowq16 + 16 * i) * D + chunk * 8];
            vreg[i] = *(const bf16x8*)&vb[(size_t)(dRow + 32 * i) * S + c3 * 8];
        }

        for (int kt = 0; kt <= qblk; ++kt) {
            __syncthreads();                      // prior tile's readers done
#pragma unroll
            for (int i = 0; i < 4; ++i) {
                *(bf16x8*)&Kl[rowq16 + 16 * i][chunk * 8] = kreg[i];
                *(bf16x8*)&Vt[dRow + 32 * i][c3 * 8] = vreg[i];
            }
            if (kt < qblk) {                      // prefetch next tile
                const int kn = kt + 1;
#pragma unroll
                for (int i = 0; i < 4; ++i) {
                    kreg[i] = *(const bf16x8*)&kb[(size_t)(kn * 64 + rowq16 + 16 * i) * D + chunk * 8];
                    vreg[i] = *(const bf16x8*)&vb[(size_t)(dRow + 32 * i) * S + kn * 64 + c3 * 8];
                }
            }
            __syncthreads();                      // LDS tiles visible

            // S = Q(16x128) @ K_tile^T(128x64)
            f32x4 sacc[4];
#pragma unroll
            for (int c = 0; c < 4; ++c) sacc[c] = (f32x4){0.f, 0.f, 0.f, 0.f};
#pragma unroll
            for (int kk = 0; kk < 4; ++kk) {
#pragma unroll
                for (int c = 0; c < 4; ++c) {
                    bf16x8 bfrag = *(const bf16x8*)&Kl[c * 16 + col][kk * 32 + quad * 8];
                    sacc[c] = __builtin_amdgcn_mfma_f32_16x16x32_bf16(qf[kk], bfrag, sacc[c], 0, 0, 0);
                }
            }

            // scale to log2 domain + causal mask (diagonal tile only)
            float sv[4][4];
            const bool diag = (kt == qblk);
#pragma unroll
            for (int c = 0; c < 4; ++c) {
#pragma unroll
                for (int r = 0; r < 4; ++r) {
                    float val = sacc[c][r] * kscale;
                    if (diag) {
                        const int key = c * 16 + col;
                        const int qrow = wv * 16 + quad * 4 + r;
                        if (key > qrow) val = -INFINITY;
                    }
                    sv[c][r] = val;
                }
            }

            // online softmax (exp2 domain, deferred l-reduce)
#pragma unroll
            for (int r = 0; r < 4; ++r) {
                float mt = fmaxf(fmaxf(sv[0][r], sv[1][r]), fmaxf(sv[2][r], sv[3][r]));
#pragma unroll
                for (int off = 1; off < 16; off <<= 1) mt = fmaxf(mt, __shfl_xor(mt, off));
                const float mnew = fmaxf(mrun[r], mt);
                const float alpha = exp2f(mrun[r] - mnew);
                mrun[r] = mnew;
                float lad = 0.f;
#pragma unroll
                for (int c = 0; c < 4; ++c) {
                    const float p = exp2f(sv[c][r] - mnew);
                    sv[c][r] = p;
                    lad += p;
                }
                lrun[r] = lrun[r] * alpha + lad;   // per-lane partial
#pragma unroll
                for (int dt = 0; dt < 8; ++dt) oacc[dt][r] *= alpha;
            }

            // P: C-layout regs -> per-wave LDS (no cross-wave sync needed)
#pragma unroll
            for (int c = 0; c < 4; ++c)
#pragma unroll
                for (int r = 0; r < 4; ++r)
                    Pl[wv][quad * 4 + r][c * 16 + col] = (__bf16)sv[c][r];

            // O += P(16x64) @ V(64x128)
#pragma unroll
            for (int ks = 0; ks < 2; ++ks) {
                bf16x8 af = *(const bf16x8*)&Pl[wv][col][ks * 32 + quad * 8];
#pragma unroll
                for (int dt = 0; dt < 8; ++dt) {
                    bf16x8 bfrag = *(const bf16x8*)&Vt[dt * 16 + col][ks * 32 + quad * 8];
                    oacc[dt] = __builtin_amdgcn_mfma_f32_16x16x32_bf16(af, bfrag, oacc[dt], 0, 0, 0);
                }
            }
        }

        // epilogue: final l reduce across the 16 lanes, normalize, store
#pragma unroll
        for (int r = 0; r < 4; ++r) {
            float l = lrun[r];
#pragma unroll
            for (int off = 1; off < 16; off <<= 1) l += __shfl_xor(l, off);
            const float inv_l = 1.0f / l;
            const int qrow = q0 + wv * 16 + quad * 4 + r;
            float* ob = out + ((size_t)h * S + qrow) * D;
#pragma unroll
            for (int dt = 0; dt < 8; ++dt)
                ob[dt * 16 + col] = oacc[dt][r] * inv_l;
        }
    }
}

// ---------------------------------------------------------------------------
extern "C" void kernel_launch(void* const* d_in, const int* in_sizes, int n_in,
                              void* d_out, int out_size, void* d_ws, size_t ws_size,
                              hipStream_t stream) {
    const float* Q = (const float*)d_in[0];
    const float* K = (const float*)d_in[1];
    const float* V = (const float*)d_in[2];
    float* out = (float*)d_out;

    char* ws = (char*)d_ws;
    const size_t nElem = (size_t)H * S * D;                  // 8,388,608
    __bf16* k_rec = (__bf16*)ws;                             // 16.78 MB
    __bf16* vT    = (__bf16*)(ws + nElem * 2);               // 16.78 MB
    float*  cand  = (float*)(ws + nElem * 4);                // 4096*272*4 = 4.46 MB
    float2* ktab  = (float2*)(ws + nElem * 4 + (size_t)4096 * 272 * 4);  // 32 KB

    kstats_kernel<<<dim3(8, H), 256, 0, stream>>>(K, cand);
    vrecon_kernel<<<dim3(S / 64, H), 256, 0, stream>>>(V, vT);
    kmerge_kernel<<<dim3(16), 256, 0, stream>>>(cand, ktab);
    kapply_kernel<<<dim3(nElem / 1024), 256, 0, stream>>>(K, ktab, k_rec);
    attn_kernel<<<dim3(16, H), 256, 0, stream>>>(Q, k_rec, vT, out);
}

// Round 3
// 332.939 us; speedup vs baseline: 1.4668x; 1.1325x over previous
//
#include <hip/hip_runtime.h>
#include <math.h>

// B=1, H=32, S=2048, D=128, N_OUT=16, QMAX=7, EPS=1e-6
// Top-k indices never needed: only 16th (outlier threshold, kept exact) and
// 17th (scale) order statistics of |x| per slice.

typedef __bf16 bf16x8 __attribute__((ext_vector_type(8)));
typedef __bf16 bf16x4 __attribute__((ext_vector_type(4)));
typedef float f32x4 __attribute__((ext_vector_type(4)));

#define H 32
#define S 2048
#define D 128

// Branch-free descending top-17 insert: t[j] = med3(x, t[j-1], t[j]).
__device__ __forceinline__ void ins17(float t[17], float x) {
#pragma unroll
    for (int j = 16; j >= 1; --j) t[j] = __builtin_amdgcn_fmed3f(x, t[j - 1], t[j]);
    t[0] = fmaxf(t[0], x);
}

// ---------------------------------------------------------------------------
// K stats phase 1: per-(h,ch) partial top-17 over 256-token chunks.
// 2 ILP chains per thread + ts-pair merge in LDS -> 8 lists per (h,ch).
// ---------------------------------------------------------------------------
__global__ __launch_bounds__(256) void kstats_kernel(const float* __restrict__ K,
                                                     float* __restrict__ cand) {
    __shared__ float ml[128][17];
    const int h = blockIdx.y, tc = blockIdx.x;         // 8 chunks x 256 tokens
    const int ch = threadIdx.x & 127, ts = threadIdx.x >> 7;
    const float* p = K + ((size_t)h * S + tc * 256 + ts * 128) * D + ch;
    float ta[17], tb[17];
#pragma unroll
    for (int j = 0; j < 17; ++j) { ta[j] = -1.f; tb[j] = -1.f; }
#pragma unroll 8
    for (int i = 0; i < 64; ++i) {
        ins17(ta, fabsf(p[(size_t)i * D]));
        ins17(tb, fabsf(p[(size_t)(i + 64) * D]));
    }
#pragma unroll
    for (int j = 0; j < 17; ++j) ins17(ta, tb[j]);
    if (ts == 1) {
#pragma unroll
        for (int j = 0; j < 17; ++j) ml[ch][j] = ta[j];
    }
    __syncthreads();
    if (ts == 0) {
#pragma unroll
        for (int j = 0; j < 17; ++j) ins17(ta, ml[ch][j]);
        float* o = cand + ((size_t)(h * 128 + ch) * 8 + tc) * 17;
#pragma unroll
        for (int j = 0; j < 17; ++j) o[j] = ta[j];
    }
}

// ---------------------------------------------------------------------------
// K stats phase 2: merge 8 partial lists (136 floats) -> thr16 + scale.
// 4 interleaved chains to beat the med3 dependency latency.
// ---------------------------------------------------------------------------
__global__ __launch_bounds__(256) void kmerge_kernel(const float* __restrict__ cand,
                                                     float2* __restrict__ ktab) {
    const int g = blockIdx.x * 256 + threadIdx.x;      // (h*128+ch), 4096 total
    const float* p = cand + (size_t)g * 136;
    float t0[17], t1[17], t2[17], t3[17];
#pragma unroll
    for (int j = 0; j < 17; ++j) { t0[j] = -1.f; t1[j] = -1.f; t2[j] = -1.f; t3[j] = -1.f; }
#pragma unroll 2
    for (int i = 0; i < 34; ++i) {
        ins17(t0, p[i]);
        ins17(t1, p[34 + i]);
        ins17(t2, p[68 + i]);
        ins17(t3, p[102 + i]);
    }
#pragma unroll
    for (int j = 0; j < 17; ++j) { ins17(t0, t1[j]); ins17(t2, t3[j]); }
#pragma unroll
    for (int j = 0; j < 17; ++j) ins17(t0, t2[j]);
    ktab[g] = make_float2(t0[15], fmaxf(t0[16], 1e-6f) / 7.0f);
}

// ---------------------------------------------------------------------------
// K apply: elementwise fake-quant, fully coalesced.
// ---------------------------------------------------------------------------
__global__ __launch_bounds__(256) void kapply_kernel(const float* __restrict__ K,
                                                     const float2* __restrict__ ktab,
                                                     __bf16* __restrict__ k_rec) {
    const size_t base = ((size_t)blockIdx.x * 256 + threadIdx.x) * 4;
    const int h = (int)(base >> 18);            // S*D = 2^18
    const int d0 = (int)(base & (D - 1));
    const float4 x = *(const float4*)(K + base);
    const float2* tp = ktab + h * D + d0;
    float xs[4] = {x.x, x.y, x.z, x.w};
    bf16x4 o;
#pragma unroll
    for (int c = 0; c < 4; ++c) {
        const float2 tc = tp[c];
        float v;
        if (fabsf(xs[c]) >= tc.x) v = xs[c];
        else {
            float q = rintf(xs[c] / tc.y);
            q = fminf(fmaxf(q, -7.f), 7.f);
            v = q * tc.y;
        }
        o[c] = (__bf16)v;
    }
    *(bf16x4*)(k_rec + base) = o;
}

// ---------------------------------------------------------------------------
// V stats: one thread per (h,s) row, 128 channels, 2 ILP med3 chains.
// ---------------------------------------------------------------------------
__global__ __launch_bounds__(256) void vstats_kernel(const float* __restrict__ V,
                                                     float2* __restrict__ vtab) {
    const int row = blockIdx.x * 256 + threadIdx.x;    // 65536 rows
    const float4* p = (const float4*)(V + (size_t)row * D);
    float ta[17], tb[17];
#pragma unroll
    for (int j = 0; j < 17; ++j) { ta[j] = -1.f; tb[j] = -1.f; }
#pragma unroll 4
    for (int i = 0; i < 16; ++i) {
        const float4 a = p[i], b = p[i + 16];
        ins17(ta, fabsf(a.x)); ins17(ta, fabsf(a.y));
        ins17(ta, fabsf(a.z)); ins17(ta, fabsf(a.w));
        ins17(tb, fabsf(b.x)); ins17(tb, fabsf(b.y));
        ins17(tb, fabsf(b.z)); ins17(tb, fabsf(b.w));
    }
#pragma unroll
    for (int j = 0; j < 17; ++j) ins17(ta, tb[j]);
    vtab[row] = make_float2(ta[15], fmaxf(ta[16], 1e-6f) / 7.0f);
}

// ---------------------------------------------------------------------------
// V apply: recon + transpose to vT[h][d][s] (bf16), pure bandwidth.
// ---------------------------------------------------------------------------
__global__ __launch_bounds__(256) void vapply_kernel(const float* __restrict__ V,
                                                     const float2* __restrict__ vtab,
                                                     __bf16* __restrict__ vT) {
    __shared__ __bf16 tile[128][72];
    const int h = blockIdx.y;
    const int s0 = blockIdx.x * 64;
    const int wv = threadIdx.x >> 6;
    const int lane = threadIdx.x & 63;

#pragma unroll
    for (int g = 0; g < 2; ++g) {
        bf16x8 b0, b1;
#pragma unroll
        for (int it = 0; it < 8; ++it) {
            const int s = s0 + wv * 16 + g * 8 + it;
            const float2 tc = vtab[h * S + s];
            const float* row = V + ((size_t)h * S + s) * D;
            const float a = row[lane], b = row[lane + 64];
            float o0, o1;
            if (fabsf(a) >= tc.x) o0 = a;
            else { float q = rintf(a / tc.y); q = fminf(fmaxf(q, -7.f), 7.f); o0 = q * tc.y; }
            if (fabsf(b) >= tc.x) o1 = b;
            else { float q = rintf(b / tc.y); q = fminf(fmaxf(q, -7.f), 7.f); o1 = q * tc.y; }
            b0[it] = (__bf16)o0;
            b1[it] = (__bf16)o1;
        }
        *(bf16x8*)&tile[lane][wv * 16 + g * 8] = b0;
        *(bf16x8*)&tile[lane + 64][wv * 16 + g * 8] = b1;
    }
    __syncthreads();
    const int dRow = threadIdx.x >> 3;
    const int c3 = threadIdx.x & 7;
#pragma unroll
    for (int i = 0; i < 4; ++i) {
        const int d = dRow + 32 * i;
        bf16x8 val = *(const bf16x8*)&tile[d][c3 * 8];
        *(bf16x8*)&vT[((size_t)h * D + d) * S + s0 + c3 * 8] = val;
    }
}

// ---------------------------------------------------------------------------
// Causal flash attention, S^T formulation.
// S^T = K_tile(64x128) @ Q^T(128x16): per-lane C-layout holds key=c*16+quad*4+r,
// q=col -> softmax is IN-LANE (15 max) + 2 cross-quad shuffles; alpha is one
// scalar/lane; P packs to 4x ds_write_b64. 1024 blocks, heavy-first.
// ---------------------------------------------------------------------------
__global__ __launch_bounds__(256, 3) void attn_kernel(const float* __restrict__ Q,
                                                      const __bf16* __restrict__ k_rec,
                                                      const __bf16* __restrict__ vT,
                                                      float* __restrict__ out) {
    __shared__ __bf16 Kl[64][136];
    __shared__ __bf16 Vt[128][72];
    __shared__ __bf16 Pl[4][16][72];

    const int h = blockIdx.y;
    const int qblk = 31 - blockIdx.x;        // heavy blocks dispatch first
    const int tid = threadIdx.x;
    const int wv = tid >> 6;
    const int lane = tid & 63;
    const int quad = lane >> 4;
    const int col = lane & 15;
    const int rowq16 = tid >> 4, chunk = tid & 15;   // K staging
    const int dRow = tid >> 3, c3 = tid & 7;         // V staging
    const __bf16* kb = k_rec + (size_t)h * S * D;
    const __bf16* vb = vT + (size_t)h * D * S;
    const float kscale = 0.08838834764831845f * 1.4426950408889634f;  // 1/sqrt(D)*log2e
    const int q0 = qblk * 64;

    // Q fragments (B-operand layout: n=col=q, k=quad*8+j), fp32->bf16 once
    bf16x8 qf[4];
    {
        const float* qbase = Q + ((size_t)h * S + q0 + wv * 16 + col) * D + quad * 8;
#pragma unroll
        for (int kk = 0; kk < 4; ++kk) {
            const float4 a = *(const float4*)(qbase + kk * 32);
            const float4 b = *(const float4*)(qbase + kk * 32 + 4);
            qf[kk] = (bf16x8){(__bf16)a.x, (__bf16)a.y, (__bf16)a.z, (__bf16)a.w,
                              (__bf16)b.x, (__bf16)b.y, (__bf16)b.z, (__bf16)b.w};
        }
    }

    f32x4 oacc[8];
#pragma unroll
    for (int dt = 0; dt < 8; ++dt) oacc[dt] = (f32x4){0.f, 0.f, 0.f, 0.f};
    float mrun = -INFINITY;
    float lrun = 0.f;                        // per-lane (per-quad) partial sum

    // prefetch tile 0
    bf16x8 kreg[4], vreg[4];
#pragma unroll
    for (int i = 0; i < 4; ++i) {
        kreg[i] = *(const bf16x8*)&kb[(size_t)(rowq16 + 16 * i) * D + chunk * 8];
        vreg[i] = *(const bf16x8*)&vb[(size_t)(dRow + 32 * i) * S + c3 * 8];
    }

    for (int kt = 0; kt <= qblk; ++kt) {
        __syncthreads();
#pragma unroll
        for (int i = 0; i < 4; ++i) {
            *(bf16x8*)&Kl[rowq16 + 16 * i][chunk * 8] = kreg[i];
            *(bf16x8*)&Vt[dRow + 32 * i][c3 * 8] = vreg[i];
        }
        if (kt < qblk) {
            const int kn = kt + 1;
#pragma unroll
            for (int i = 0; i < 4; ++i) {
                kreg[i] = *(const bf16x8*)&kb[(size_t)(kn * 64 + rowq16 + 16 * i) * D + chunk * 8];
                vreg[i] = *(const bf16x8*)&vb[(size_t)(dRow + 32 * i) * S + kn * 64 + c3 * 8];
            }
        }
        __syncthreads();

        // S^T = K_tile @ Q^T : A = K rows (m=key), B = Q (n=q)
        f32x4 sacc[4];
#pragma unroll
        for (int c = 0; c < 4; ++c) sacc[c] = (f32x4){0.f, 0.f, 0.f, 0.f};
#pragma unroll
        for (int kk = 0; kk < 4; ++kk) {
#pragma unroll
            for (int c = 0; c < 4; ++c) {
                bf16x8 kfrag = *(const bf16x8*)&Kl[c * 16 + col][kk * 32 + quad * 8];
                sacc[c] = __builtin_amdgcn_mfma_f32_16x16x32_bf16(kfrag, qf[kk], sacc[c], 0, 0, 0);
            }
        }

        // scale to log2 domain + causal mask (diag tile only)
        float sv[4][4];
        const bool diag = (kt == qblk);
        const int qloc = wv * 16 + col;
#pragma unroll
        for (int c = 0; c < 4; ++c) {
#pragma unroll
            for (int r = 0; r < 4; ++r) {
                float val = sacc[c][r] * kscale;
                if (diag && (c * 16 + quad * 4 + r > qloc)) val = -INFINITY;
                sv[c][r] = val;
            }
        }

        // in-lane max over 16, then cross-quad
        float mt = sv[0][0];
#pragma unroll
        for (int c = 0; c < 4; ++c)
#pragma unroll
            for (int r = 0; r < 4; ++r) mt = fmaxf(mt, sv[c][r]);
        mt = fmaxf(mt, __shfl_xor(mt, 16));
        mt = fmaxf(mt, __shfl_xor(mt, 32));
        const float mnew = fmaxf(mrun, mt);
        const float alpha = exp2f(mrun - mnew);
        mrun = mnew;
        float lad = 0.f;
#pragma unroll
        for (int c = 0; c < 4; ++c)
#pragma unroll
            for (int r = 0; r < 4; ++r) {
                const float pv = exp2f(sv[c][r] - mnew);
                sv[c][r] = pv;
                lad += pv;
            }
        lrun = lrun * alpha + lad;

        // alpha for this lane's O rows (q = quad*4+r) lives at lane quad*20+r
        float ar[4];
#pragma unroll
        for (int r = 0; r < 4; ++r) ar[r] = __shfl(alpha, quad * 20 + r);
#pragma unroll
        for (int dt = 0; dt < 8; ++dt)
#pragma unroll
            for (int r = 0; r < 4; ++r) oacc[dt][r] *= ar[r];

        // P: pack 4 consecutive keys -> ds_write_b64 into Pl[q][key]
#pragma unroll
        for (int c = 0; c < 4; ++c) {
            bf16x4 pk = {(__bf16)sv[c][0], (__bf16)sv[c][1], (__bf16)sv[c][2], (__bf16)sv[c][3]};
            *(bf16x4*)&Pl[wv][col][c * 16 + quad * 4] = pk;
        }

        // O += P(16x64) @ V(64x128)
#pragma unroll
        for (int ks = 0; ks < 2; ++ks) {
            bf16x8 af = *(const bf16x8*)&Pl[wv][col][ks * 32 + quad * 8];
#pragma unroll
            for (int dt = 0; dt < 8; ++dt) {
                bf16x8 bfrag = *(const bf16x8*)&Vt[dt * 16 + col][ks * 32 + quad * 8];
                oacc[dt] = __builtin_amdgcn_mfma_f32_16x16x32_bf16(af, bfrag, oacc[dt], 0, 0, 0);
            }
        }
    }

    // epilogue: cross-quad l reduce (deferred), shuffle to O rows, store
    float l = lrun;
    l += __shfl_xor(l, 16);
    l += __shfl_xor(l, 32);
    const float linv = 1.0f / l;
    float lr[4];
#pragma unroll
    for (int r = 0; r < 4; ++r) lr[r] = __shfl(linv, quad * 20 + r);
#pragma unroll
    for (int r = 0; r < 4; ++r) {
        const int qrow = q0 + wv * 16 + quad * 4 + r;
        float* ob = out + ((size_t)h * S + qrow) * D;
#pragma unroll
        for (int dt = 0; dt < 8; ++dt)
            ob[dt * 16 + col] = oacc[dt][r] * lr[r];
    }
}

// ---------------------------------------------------------------------------
extern "C" void kernel_launch(void* const* d_in, const int* in_sizes, int n_in,
                              void* d_out, int out_size, void* d_ws, size_t ws_size,
                              hipStream_t stream) {
    const float* Q = (const float*)d_in[0];
    const float* K = (const float*)d_in[1];
    const float* V = (const float*)d_in[2];
    float* out = (float*)d_out;

    char* ws = (char*)d_ws;
    const size_t nElem = (size_t)H * S * D;                  // 8,388,608
    __bf16* k_rec = (__bf16*)ws;                             // 16.78 MB
    __bf16* vT    = (__bf16*)(ws + nElem * 2);               // 16.78 MB
    float*  cand  = (float*)(ws + nElem * 4);                // 4096*136*4 = 2.23 MB
    float2* ktab  = (float2*)(ws + nElem * 4 + (size_t)4096 * 136 * 4);          // 32 KB
    float2* vtab  = (float2*)(ws + nElem * 4 + (size_t)4096 * 136 * 4 + 32768);  // 512 KB

    kstats_kernel<<<dim3(8, H), 256, 0, stream>>>(K, cand);
    vstats_kernel<<<dim3(256), 256, 0, stream>>>(V, vtab);
    kmerge_kernel<<<dim3(16), 256, 0, stream>>>(cand, ktab);
    kapply_kernel<<<dim3(nElem / 1024), 256, 0, stream>>>(K, ktab, k_rec);
    vapply_kernel<<<dim3(S / 64, H), 256, 0, stream>>>(V, vtab, vT);
    attn_kernel<<<dim3(32, H), 256, 0, stream>>>(Q, k_rec, vT, out);
}